// Round 1
// baseline (311.752 us; speedup 1.0000x reference)
//
#include <hip/hip_runtime.h>

// GlobalMaxAvgPool: segment max + segment mean, N=2e6 rows, C=128, B=32, ids sorted.
// Memory-bound: 1.03 GB read -> floor ~164 us @ 6.3 TB/s.

#define INFF __builtin_huge_valf()

__device__ __forceinline__ unsigned enc_f32(float f) {
    // monotonic mapping float -> uint (order-preserving), enables atomicMax(uint)
    unsigned u = __float_as_uint(f);
    return (u & 0x80000000u) ? ~u : (u | 0x80000000u);
}
__device__ __forceinline__ float dec_f32(unsigned e) {
    unsigned u = (e & 0x80000000u) ? (e & 0x7FFFFFFFu) : ~e;
    return __uint_as_float(u);
}

// Re-init output accumulators every call (harness does not re-poison between replays).
__global__ void gp_init(unsigned* out_u, float* out_f, int total, int twoC, int C) {
    int i = blockIdx.x * blockDim.x + threadIdx.x;
    if (i >= total) return;
    int c = i % twoC;
    if (c < C) out_u[i] = 0x007FFFFFu;   // enc(-inf)
    else       out_f[i] = 0.0f;          // sum accumulator
}

__device__ __forceinline__ void gp_flush(unsigned* __restrict__ omax,
                                         float* __restrict__ osum,
                                         int seg, int c0,
                                         const float4& vmax, const float4& vsum) {
    int base = seg * 256 + c0;   // out layout: [B][2C], C==128
    atomicMax(&omax[base + 0], enc_f32(vmax.x));
    atomicMax(&omax[base + 1], enc_f32(vmax.y));
    atomicMax(&omax[base + 2], enc_f32(vmax.z));
    atomicMax(&omax[base + 3], enc_f32(vmax.w));
    atomicAdd(&osum[base + 128 + 0], vsum.x);
    atomicAdd(&osum[base + 128 + 1], vsum.y);
    atomicAdd(&osum[base + 128 + 2], vsum.z);
    atomicAdd(&osum[base + 128 + 3], vsum.w);
}

// C == 128 hardcoded: 32 lanes x float4 cover one row; 8 row-slots per 256-thread block.
__global__ __launch_bounds__(256, 8)
void gp_main(const float* __restrict__ feat, const int* __restrict__ ids,
             unsigned* __restrict__ omax, float* __restrict__ osum,
             int N, int chunk) {
    const int t     = threadIdx.x;
    const int slot  = t >> 5;        // 0..7  (row within 8-row group)
    const int lane5 = t & 31;        // 32 lanes per row
    const int c0    = lane5 * 4;     // 4 channels per lane

    int start = blockIdx.x * chunk;
    int end   = start + chunk;
    if (end > N) end = N;

    const float4* __restrict__ frow = reinterpret_cast<const float4*>(feat);

    float4 vmax = make_float4(-INFF, -INFF, -INFF, -INFF);
    float4 vsum = make_float4(0.f, 0.f, 0.f, 0.f);
    int cur = -1;

    for (int r = start + slot; r < end; r += 8) {
        int id = ids[r];                       // wave-broadcast, L1-hot
        if (id != cur) {                       // rare: 31 boundaries total in N
            if (cur >= 0) gp_flush(omax, osum, cur, c0, vmax, vsum);
            cur  = id;
            vmax = make_float4(-INFF, -INFF, -INFF, -INFF);
            vsum = make_float4(0.f, 0.f, 0.f, 0.f);
        }
        float4 f = frow[(size_t)r * 32 + lane5];   // 16B/lane coalesced
        vmax.x = fmaxf(vmax.x, f.x);
        vmax.y = fmaxf(vmax.y, f.y);
        vmax.z = fmaxf(vmax.z, f.z);
        vmax.w = fmaxf(vmax.w, f.w);
        vsum.x += f.x;
        vsum.y += f.y;
        vsum.z += f.z;
        vsum.w += f.w;
    }
    if (cur >= 0) gp_flush(omax, osum, cur, c0, vmax, vsum);
}

__device__ __forceinline__ int lower_bound_i(const int* __restrict__ a, int n, int v) {
    int lo = 0, hi = n;
    while (lo < hi) {
        int mid = (lo + hi) >> 1;
        if (a[mid] < v) lo = mid + 1; else hi = mid;
    }
    return lo;
}

// One block per segment: decode max-encoding in place, divide sums by count.
// Counts via binary search on sorted ids -- no atomics needed.
__global__ void gp_final(float* out, const int* __restrict__ ids, int N, int C) {
    int b = blockIdx.x;
    int c = threadIdx.x;   // 0..C-1
    int cnt = lower_bound_i(ids, N, b + 1) - lower_bound_i(ids, N, b);
    unsigned* ou = reinterpret_cast<unsigned*>(out);
    int base = b * 2 * C;
    float mx = dec_f32(ou[base + c]);
    float s  = out[base + C + c];
    out[base + c]     = mx;
    out[base + C + c] = s / fmaxf((float)cnt, 1.0f);
}

extern "C" void kernel_launch(void* const* d_in, const int* in_sizes, int n_in,
                              void* d_out, int out_size, void* d_ws, size_t ws_size,
                              hipStream_t stream) {
    const float* feat = (const float*)d_in[0];
    const int*   ids  = (const int*)d_in[1];
    int N = in_sizes[1];
    int C = (N > 0) ? (in_sizes[0] / N) : 128;   // 128
    int B = out_size / (2 * C);                  // 32
    float*    out_f = (float*)d_out;
    unsigned* out_u = (unsigned*)d_out;

    // 1) init accumulators in d_out
    gp_init<<<(out_size + 255) / 256, 256, 0, stream>>>(out_u, out_f, out_size, 2 * C, C);

    // 2) main pass: contiguous chunks, register accumulation, flush-on-boundary
    const int blocks = 2048;
    int chunk = (N + blocks - 1) / blocks;
    gp_main<<<blocks, 256, 0, stream>>>(feat, ids, out_u, out_f, N, chunk);

    // 3) finalize: decode max, divide sum by binary-searched counts
    gp_final<<<B, C, 0, stream>>>(out_f, ids, N, C);
}

// Round 2
// 291.679 us; speedup vs baseline: 1.0688x; 1.0688x over previous
//
#include <hip/hip_runtime.h>

// GlobalMaxAvgPool: segment max + segment mean, N=2e6 rows, C=128, B=32, ids sorted.
// Memory-bound: 1.025 GB feature read -> floor ~164 us @ 6.3 TB/s.
// R1: branch-free streaming inner loop. Segment boundaries precomputed once
// (33 binary searches) so gp_main never loads ids -> no dependent branch,
// compiler can unroll and keep 4 feature loads in flight per wave.

#define INFF __builtin_huge_valf()

__device__ __forceinline__ unsigned enc_f32(float f) {
    // monotonic float->uint (order-preserving) so atomicMax(uint) works
    unsigned u = __float_as_uint(f);
    return (u & 0x80000000u) ? ~u : (u | 0x80000000u);
}
__device__ __forceinline__ float dec_f32(unsigned e) {
    unsigned u = (e & 0x80000000u) ? (e & 0x7FFFFFFFu) : ~e;
    return __uint_as_float(u);
}

__device__ __forceinline__ int lower_bound_i(const int* __restrict__ a, int n, int v) {
    int lo = 0, hi = n;
    while (lo < hi) {
        int mid = (lo + hi) >> 1;
        if (a[mid] < v) lo = mid + 1; else hi = mid;
    }
    return lo;
}

// Kernel 0: re-init out accumulators (harness doesn't re-poison between replays)
// + compute segment start offsets seg_starts[0..B] into workspace.
__global__ void gp_prep(unsigned* out_u, float* out_f, int out_total, int C,
                        const int* __restrict__ ids, int N, int B,
                        int* __restrict__ seg_starts) {
    int i = blockIdx.x * blockDim.x + threadIdx.x;
    if (i < out_total) {
        int c = i % (2 * C);
        if (c < C) out_u[i] = 0x007FFFFFu;   // enc(-inf)
        else       out_f[i] = 0.0f;          // sum accumulator
    }
    if (i <= B) {
        // first row index with ids[r] >= i ; seg_starts[B] == N
        seg_starts[i] = lower_bound_i(ids, N, i);
    }
}

__device__ __forceinline__ void gp_flush(unsigned* __restrict__ omax,
                                         float* __restrict__ osum,
                                         int seg, int c0,
                                         const float4& vmax, const float4& vsum) {
    int base = seg * 256 + c0;   // out layout: [B][2C], C==128
    atomicMax(&omax[base + 0], enc_f32(vmax.x));
    atomicMax(&omax[base + 1], enc_f32(vmax.y));
    atomicMax(&omax[base + 2], enc_f32(vmax.z));
    atomicMax(&omax[base + 3], enc_f32(vmax.w));
    atomicAdd(&osum[base + 128 + 0], vsum.x);
    atomicAdd(&osum[base + 128 + 1], vsum.y);
    atomicAdd(&osum[base + 128 + 2], vsum.z);
    atomicAdd(&osum[base + 128 + 3], vsum.w);
}

// C == 128 hardcoded: 32 lanes x float4 = one row; 8 row-slots per 256-thread block.
__global__ __launch_bounds__(256, 8)
void gp_main(const float* __restrict__ feat,
             const int* __restrict__ seg_starts,
             unsigned* __restrict__ omax, float* __restrict__ osum,
             int N, int chunk, int B) {
    const int t     = threadIdx.x;
    const int slot  = t >> 5;        // 0..7
    const int lane5 = t & 31;
    const int c0    = lane5 * 4;

    int start = blockIdx.x * chunk;
    int end   = start + chunk;
    if (end > N) end = N;
    if (start >= end) return;

    __shared__ int sb[40];           // seg_starts[0..B], B==32
    if (t <= B) sb[t] = seg_starts[t];
    __syncthreads();

    // segment containing 'start': largest s with sb[s] <= start (uniform scan, 32 iters)
    int seg = 0;
    #pragma unroll
    for (int s = 1; s < 33; ++s)
        if (s <= B && sb[s] <= start) seg = s;

    const float4* __restrict__ frow = reinterpret_cast<const float4*>(feat);

    int rs = start;
    while (rs < end) {
        int re = sb[seg + 1];
        if (re > end) re = end;
        if (rs + slot < re) {
            float4 vmax = make_float4(-INFF, -INFF, -INFF, -INFF);
            float4 vsum = make_float4(0.f, 0.f, 0.f, 0.f);
            #pragma unroll 4
            for (int r = rs + slot; r < re; r += 8) {
                float4 f = frow[(size_t)r * 32 + lane5];   // 16B/lane, 1KB/wave, coalesced
                vmax.x = fmaxf(vmax.x, f.x);
                vmax.y = fmaxf(vmax.y, f.y);
                vmax.z = fmaxf(vmax.z, f.z);
                vmax.w = fmaxf(vmax.w, f.w);
                vsum.x += f.x;
                vsum.y += f.y;
                vsum.z += f.z;
                vsum.w += f.w;
            }
            gp_flush(omax, osum, seg, c0, vmax, vsum);
        }
        ++seg;
        rs = re;
    }
}

// One block per segment: decode max in place, divide sums by count from boundaries.
__global__ void gp_final(float* out, const int* __restrict__ seg_starts, int C) {
    int b = blockIdx.x;
    int c = threadIdx.x;   // 0..C-1
    int cnt = seg_starts[b + 1] - seg_starts[b];
    unsigned* ou = reinterpret_cast<unsigned*>(out);
    int base = b * 2 * C;
    float mx = dec_f32(ou[base + c]);
    float s  = out[base + C + c];
    out[base + c]     = mx;
    out[base + C + c] = s / fmaxf((float)cnt, 1.0f);
}

extern "C" void kernel_launch(void* const* d_in, const int* in_sizes, int n_in,
                              void* d_out, int out_size, void* d_ws, size_t ws_size,
                              hipStream_t stream) {
    const float* feat = (const float*)d_in[0];
    const int*   ids  = (const int*)d_in[1];
    int N = in_sizes[1];
    int C = (N > 0) ? (in_sizes[0] / N) : 128;   // 128
    int B = out_size / (2 * C);                  // 32
    float*    out_f = (float*)d_out;
    unsigned* out_u = (unsigned*)d_out;
    int* seg_starts = (int*)d_ws;                // B+1 ints of scratch

    // 1) init accumulators + boundaries (covers max(out_size, B+1) threads)
    int prep_threads = out_size > (B + 1) ? out_size : (B + 1);
    gp_prep<<<(prep_threads + 255) / 256, 256, 0, stream>>>(
        out_u, out_f, out_size, C, ids, N, B, seg_starts);

    // 2) main pass: branch-free streaming over precomputed runs
    const int blocks = 2048;
    int chunk = (N + blocks - 1) / blocks;
    gp_main<<<blocks, 256, 0, stream>>>(feat, seg_starts, out_u, out_f, N, chunk, B);

    // 3) finalize: decode max, divide sum by count
    gp_final<<<B, C, 0, stream>>>(out_f, seg_starts, C);
}